// Round 3
// baseline (225.918 us; speedup 1.0000x reference)
//
#include <hip/hip_runtime.h>
#include <hip/hip_bf16.h>

// InfoNCE loss, fused flash-style:
//   loss = (1/B) * sum_i [ log(sum_j exp(Q_i . D_j / T)) - Q_i . D_{i*dp} / T ]
// Logits bounded (|logit| < ~10) -> no max-subtraction; per-row sum-exp is
// commutative -> atomicAdd merge across column-blocks.
//
// R3 changes vs R2:
//  - fragment-order LDS layout: chunk c=(rb,s) of 1KB holds exactly one
//    wave-fragment set; both the global_load_lds writes AND the ds_read_b128
//    fragment reads are lane-linear (64 consecutive 16B slots per wave) ->
//    bank-conflict-free by construction. (R2's segment swizzle provably
//    changed nothing: conflict count identical at 4 cyc/read.)
//  - pos-logit extracted from the GEMM accumulators in the epilogue
//    (bf16 noise ~0.02 per logit, threshold 0.205 on a 4096-row mean):
//    block (bx,by) owns row gr's positive iff gr*dp - dbase in [0,128).
//  - cvt back to flat streaming form (no per-row blocks, no pos D reads).
//
// ws layout (~24.1 MB):
//   [0)        Qbf  B*K bf16    (8 MB)
//   [B*K*2)    Dbf  N*K bf16    (16 MB)
//   [+N*K*2)   rowsum B f32     (16 KB)  zeroed by cvt kernel
//   [+B*4)     pos    B f32     (16 KB)  written by gemm epilogue

#define BM 128
#define BN 128
#define BK 32
#define TEMP_INV 50.0f

typedef __bf16 bf16x8 __attribute__((ext_vector_type(8)));
typedef float f32x4 __attribute__((ext_vector_type(4)));

__device__ inline unsigned short f2bf(float f) {
    union { float f; unsigned int u; } x; x.f = f;
    unsigned int r = x.u + 0x7fffu + ((x.u >> 16) & 1u);   // RNE
    return (unsigned short)(r >> 16);
}

// ---------------- flat convert fp32 -> bf16, zero rowsum ----------------
__global__ void cvt_kernel(const float* __restrict__ Q, const float* __restrict__ Dm,
                           unsigned short* __restrict__ Qb, unsigned short* __restrict__ Db,
                           float* __restrict__ rowsum, int qElems, int dElems, int B) {
    int gid = blockIdx.x * blockDim.x + threadIdx.x;
    if (gid < B) rowsum[gid] = 0.0f;
    int idx = gid * 4;
    if (idx < qElems) {
        float4 v = *(const float4*)(Q + idx);
        ushort4 o;
        o.x = f2bf(v.x); o.y = f2bf(v.y); o.z = f2bf(v.z); o.w = f2bf(v.w);
        *(ushort4*)(Qb + idx) = o;
    } else if (idx < qElems + dElems) {
        int d = idx - qElems;
        float4 v = *(const float4*)(Dm + d);
        ushort4 o;
        o.x = f2bf(v.x); o.y = f2bf(v.y); o.z = f2bf(v.z); o.w = f2bf(v.w);
        *(ushort4*)(Db + d) = o;
    }
}

// ---------------- fused bf16 GEMM + row sum-exp + pos extraction ------------
// grid: (B/BM, N/BN); block: 256 (4 waves), 128x128 tile, BK=32.
//
// Fragment-order LDS: tile = 8 chunks of 1KB. Chunk c=(rb=c>>1, s=c&1) slot
// l (16B) holds A[rb*32 + (l&31)][k0 + s*16 + (l>>5)*8 ..+8]. Staging wave w
// writes chunks {2w,2w+1} lane-linearly (LDS dest = chunk base + lane*16, as
// global_load_lds requires); the permutation lives in the per-lane GLOBAL
// source address. Fragment read af[i] (rows wrow+16i+lm, k=lquad*8..+8)
// decodes to chunk ((wrow>>5)+(i>>1))*2+(lquad>>1), slot (lquad&1)*32 +
// 16*(i&1) + lm -> each wave reads 4 runs of 16 consecutive 16B slots:
// conflict-free (stride-1 pattern, m134).
__global__ __launch_bounds__(256, 2) void gemm_expsum_kernel(
        const unsigned short* __restrict__ Qb, const unsigned short* __restrict__ Db,
        const int* __restrict__ dper,
        float* __restrict__ rowsum, float* __restrict__ pos, int K) {
    __shared__ unsigned short Qs[BM * BK];   // 8KB, fragment-order
    __shared__ unsigned short Ds[BN * BK];

    const int qbase = blockIdx.x * BM;
    const int dbase = blockIdx.y * BN;
    const int tid   = threadIdx.x;
    const int wave  = tid >> 6;
    const int lane  = tid & 63;
    const int wrow  = (wave >> 1) * 64;   // wave quadrant in 128x128 tile
    const int wcol  = (wave & 1) * 64;
    const int lquad = lane >> 4;
    const int lm    = lane & 15;

    // staging source (chunk c = 2*wave + q): row rb*32+(lane&31), rb=wave
    const int srow  = wave * 32 + (lane & 31);
    const int skoff = (lane >> 5) * 8;     // + q*16 at use site

    // fragment-read base (elems): chunk*512 + slot*8
    const int fbase = (lquad >> 1) * 512 + (lquad & 1) * 256 + lm * 8;
    const int abase = wrow * 32 + fbase;
    const int bbase = wcol * 32 + fbase;

    const unsigned short* Qtile = Qb + (size_t)qbase * K;
    const unsigned short* Dtile = Db + (size_t)dbase * K;

    f32x4 acc[16];
#pragma unroll
    for (int t = 0; t < 16; ++t) acc[t] = (f32x4){0.f, 0.f, 0.f, 0.f};

    for (int k0 = 0; k0 < K; k0 += BK) {
#pragma unroll
        for (int q = 0; q < 2; ++q) {
            const int c = wave * 2 + q;
            const int gk = k0 + q * 16 + skoff;
            const unsigned short* g1 = Qtile + (size_t)srow * K + gk;
            unsigned short* l1 = Qs + c * 512 + lane * 8;
            __builtin_amdgcn_global_load_lds(
                (const __attribute__((address_space(1))) void*)g1,
                (__attribute__((address_space(3))) void*)l1, 16, 0, 0);
            const unsigned short* g2 = Dtile + (size_t)srow * K + gk;
            unsigned short* l2 = Ds + c * 512 + lane * 8;
            __builtin_amdgcn_global_load_lds(
                (const __attribute__((address_space(1))) void*)g2,
                (__attribute__((address_space(3))) void*)l2, 16, 0, 0);
        }
        __syncthreads();   // drains vmcnt -> LDS tiles ready

        bf16x8 af[4], bfv[4];
#pragma unroll
        for (int i = 0; i < 4; ++i)
            af[i] = *(const bf16x8*)(Qs + abase + (i >> 1) * 1024 + (i & 1) * 128);
#pragma unroll
        for (int j = 0; j < 4; ++j)
            bfv[j] = *(const bf16x8*)(Ds + bbase + (j >> 1) * 1024 + (j & 1) * 128);
#pragma unroll
        for (int i = 0; i < 4; ++i)
#pragma unroll
            for (int j = 0; j < 4; ++j)
                acc[i * 4 + j] = __builtin_amdgcn_mfma_f32_16x16x32_bf16(
                    af[i], bfv[j], acc[i * 4 + j], 0, 0, 0);
        __syncthreads();   // all waves done reading before next stage
    }

    // epilogue. C layout: col = lane&15, row = (lane>>4)*4 + reg  [m89/m91]
    const int dp = dper[0];
#pragma unroll
    for (int i = 0; i < 4; ++i)
#pragma unroll
        for (int r = 0; r < 4; ++r) {
            const int gr   = qbase + wrow + 16 * i + 4 * lquad + r;
            const int pcol = gr * dp - dbase;   // local col of positive, if here
            float e = 0.0f;
#pragma unroll
            for (int j = 0; j < 4; ++j) {
                float v = acc[i * 4 + j][r];
                if (wcol + 16 * j + lm == pcol) pos[gr] = v * TEMP_INV;
                e += __expf(v * TEMP_INV);
            }
            e += __shfl_xor(e, 1);
            e += __shfl_xor(e, 2);
            e += __shfl_xor(e, 4);
            e += __shfl_xor(e, 8);
            if (lm == 0) atomicAdd(&rowsum[gr], e);
        }
}

// ---------------- final: loss = sum(log(rowsum) - pos)/B ----------------
__global__ void final_kernel(const float* __restrict__ rowsum,
                             const float* __restrict__ pos,
                             float* __restrict__ out, int B) {
    __shared__ float red[16];
    int tid = threadIdx.x;   // 1024 threads
    float s = 0.0f;
    for (int i = tid; i < B; i += blockDim.x)
        s += __logf(rowsum[i]) - pos[i];
    s += __shfl_xor(s, 32);
    s += __shfl_xor(s, 16);
    s += __shfl_xor(s, 8);
    s += __shfl_xor(s, 4);
    s += __shfl_xor(s, 2);
    s += __shfl_xor(s, 1);
    int w = tid >> 6, l = tid & 63;
    if (l == 0) red[w] = s;
    __syncthreads();
    if (tid == 0) {
        float t = 0.0f;
        int nw = blockDim.x >> 6;
        for (int i = 0; i < nw; ++i) t += red[i];
        out[0] = t / (float)B;
    }
}

extern "C" void kernel_launch(void* const* d_in, const int* in_sizes, int n_in,
                              void* d_out, int out_size, void* d_ws, size_t ws_size,
                              hipStream_t stream) {
    const float* Q   = (const float*)d_in[0];
    const float* Dm  = (const float*)d_in[1];
    const int* dper  = (const int*)d_in[2];
    float* out = (float*)d_out;

    const int DIM  = 1024;
    const int B    = in_sizes[0] / DIM;   // 4096
    const int Ntot = in_sizes[1] / DIM;   // 8192

    unsigned short* Qb = (unsigned short*)d_ws;
    unsigned short* Db = Qb + (size_t)B * DIM;
    float* rowsum = (float*)(Db + (size_t)Ntot * DIM);
    float* pos = rowsum + B;

    int totalElems = (B + Ntot) * DIM;
    int cvtThreads = totalElems / 4;
    cvt_kernel<<<(cvtThreads + 255) / 256, 256, 0, stream>>>(
        Q, Dm, Qb, Db, rowsum, B * DIM, Ntot * DIM, B);

    dim3 grid(B / BM, Ntot / BN);
    gemm_expsum_kernel<<<grid, 256, 0, stream>>>(Qb, Db, dper, rowsum, pos, DIM);

    final_kernel<<<1, 1024, 0, stream>>>(rowsum, pos, out, B);
}

// Round 4
// 127.001 us; speedup vs baseline: 1.7789x; 1.7789x over previous
//
#include <hip/hip_runtime.h>

// InfoNCE loss:
//   loss = (1/B) * sum_i [ log(sum_j exp(Q_i . D_j / T)) - Q_i . D_{i*dp} / T ]
// Logits bounded (|logit| < ~10) -> no max-subtraction; per-row sum-exp is
// commutative -> atomicAdd merge across column-blocks.
//
// R4 changes vs R3:
//  - MX-fp8 path: mfma_scale_f32_16x16x128_f8f6f4 (fmt fp8), inputs
//    pre-scaled x16 before e4m3 quantization, HW scales 2^-4 * 2^-4 undo it.
//    2x MFMA rate vs bf16, half the staging bytes.
//  - PRE-TILED global layout: cvt writes the bf8 data in the exact
//    fragment-order image the GEMM's LDS wants. GEMM staging is then
//    global_load_lds of CONTIGUOUS 1KB per wave-instr (lane-linear on both
//    global and LDS sides) -> fixes R3's 32B-segment global regression while
//    keeping R3's zero LDS bank conflicts.
//  - epilogue unchanged from R3 (verified absmax 0.0): 16x16 C/D layout
//    col=lane&15, row=(lane>>4)*4+reg; pos extracted from accumulators.
//
// Tiled layout (per matrix): for 128-row block R, 128-wide k-block k0b:
//   16KB image = 16 chunks x 1KB. Chunk c = rg*2 + kh (rg=0..7 16-row group,
//   kh=0..1 64-col half); slot l (16B) holds
//   X[R*128 + rg*16 + (l&15)][k0b*128 + kh*64 + (l>>4)*16 .. +16]   (fp8)
// Wave fragment af[i]: rows (wave>>1)*64+16i+..., k quarter lquad*32..+32
// = 2 consecutive 16B slots in chunk (rg, lquad>>1) -> stride-1 slot runs.
//
// ws layout (~12.1 MB):
//   [0)       Q8  B*K fp8     (4 MB)
//   [B*K)     D8  N*K fp8     (8 MB)
//   [+N*K)    rowsum B f32    (16 KB)  zeroed by cvt kernel
//   [+B*4)    pos    B f32    (16 KB)  written by gemm epilogue

#define TEMP_INV 50.0f
#define PRESCALE 16.0f
#define SCALE_BYTE 123   // e8m0: 2^(123-127) = 2^-4 per operand

typedef int   i32x4 __attribute__((ext_vector_type(4)));
typedef int   i32x8 __attribute__((ext_vector_type(8)));
typedef float f32x4 __attribute__((ext_vector_type(4)));

// ---------------- fp32 -> fp8 e4m3 (x16), pre-tiled; zero rowsum ----------
// One thread per 16B output slot. Output stores are perfectly lane-linear;
// input reads are 64B/lane contiguous (4x float4).
__global__ void cvt_kernel(const float* __restrict__ Q, const float* __restrict__ Dm,
                           unsigned int* __restrict__ Q8, unsigned int* __restrict__ D8,
                           float* __restrict__ rowsum, int qSlots, int B, int K) {
    const int gid = blockIdx.x * blockDim.x + threadIdx.x;
    if (gid < B) rowsum[gid] = 0.0f;
    const float* src;
    unsigned int* dst;
    int s;
    if (gid < qSlots) { src = Q;  dst = Q8; s = gid; }
    else              { src = Dm; dst = D8; s = gid - qSlots; }
    const int l   = s & 63;
    const int c   = (s >> 6) & 15;
    const int k0b = (s >> 10) & 7;
    const int R   = s >> 13;
    const int row = R * 128 + (c >> 1) * 16 + (l & 15);
    const int k   = k0b * 128 + (c & 1) * 64 + (l >> 4) * 16;
    const float* p = src + (size_t)row * K + k;
    unsigned int w[4];
#pragma unroll
    for (int d = 0; d < 4; ++d) {
        float4 v = *(const float4*)(p + d * 4);
        int t = __builtin_amdgcn_cvt_pk_fp8_f32(v.x * PRESCALE, v.y * PRESCALE, 0, false);
        t = __builtin_amdgcn_cvt_pk_fp8_f32(v.z * PRESCALE, v.w * PRESCALE, t, true);
        w[d] = (unsigned int)t;
    }
    *(uint4*)(dst + (size_t)s * 4) = make_uint4(w[0], w[1], w[2], w[3]);
}

// ---------------- fused MX-fp8 GEMM + row sum-exp + pos extraction --------
// grid (B/128, N/128), 256 threads (4 waves, 2x2 wave grid), BK=128.
__global__ __launch_bounds__(256, 2) void gemm_expsum_kernel(
        const unsigned int* __restrict__ Q8, const unsigned int* __restrict__ D8,
        const int* __restrict__ dper,
        float* __restrict__ rowsum, float* __restrict__ pos, int K) {
    __shared__ unsigned int Qs[4096];   // 16KB fragment-order image
    __shared__ unsigned int Ds[4096];

    const int tid   = threadIdx.x;
    const int wave  = tid >> 6;
    const int lane  = tid & 63;
    const int lquad = lane >> 4;
    const int lm    = lane & 15;
    const int qbase = blockIdx.x * 128;
    const int dbase = blockIdx.y * 128;
    const int KB    = K >> 7;           // 8 k-blocks

    // fragment-read dword offsets: chunk(rg, kh=lquad>>1)*256 + slot*4,
    // slot = ((lquad&1)*2 + t)*16 + lm
    const int slotofs = ((lquad & 1) * 32 + lm) * 4;   // t=0; t=1 adds 64
    const int aofs = ((wave >> 1) * 8 + (lquad >> 1)) * 256 + slotofs;
    const int bofs = ((wave & 1) * 8 + (lquad >> 1)) * 256 + slotofs;

    const unsigned int* Qg = Q8 + (size_t)blockIdx.x * KB * 4096;
    const unsigned int* Dg = D8 + (size_t)blockIdx.y * KB * 4096;

    f32x4 acc[16];
#pragma unroll
    for (int t = 0; t < 16; ++t) acc[t] = (f32x4){0.f, 0.f, 0.f, 0.f};

    for (int kb = 0; kb < KB; ++kb) {
#pragma unroll
        for (int q = 0; q < 4; ++q) {
            const int c = wave * 4 + q;
            const unsigned int* g1 = Qg + kb * 4096 + c * 256 + lane * 4;
            __builtin_amdgcn_global_load_lds(
                (const __attribute__((address_space(1))) void*)g1,
                (__attribute__((address_space(3))) void*)(Qs + c * 256 + lane * 4),
                16, 0, 0);
            const unsigned int* g2 = Dg + kb * 4096 + c * 256 + lane * 4;
            __builtin_amdgcn_global_load_lds(
                (const __attribute__((address_space(1))) void*)g2,
                (__attribute__((address_space(3))) void*)(Ds + c * 256 + lane * 4),
                16, 0, 0);
        }
        __syncthreads();   // drains vmcnt -> LDS tiles ready

        i32x8 a8[4], b8[4];
#pragma unroll
        for (int i = 0; i < 4; ++i) {
            i32x4 lo = *(const i32x4*)(Qs + aofs + i * 512);
            i32x4 hi = *(const i32x4*)(Qs + aofs + i * 512 + 64);
            a8[i] = __builtin_shufflevector(lo, hi, 0, 1, 2, 3, 4, 5, 6, 7);
        }
#pragma unroll
        for (int j = 0; j < 4; ++j) {
            i32x4 lo = *(const i32x4*)(Ds + bofs + j * 512);
            i32x4 hi = *(const i32x4*)(Ds + bofs + j * 512 + 64);
            b8[j] = __builtin_shufflevector(lo, hi, 0, 1, 2, 3, 4, 5, 6, 7);
        }
#pragma unroll
        for (int i = 0; i < 4; ++i)
#pragma unroll
            for (int j = 0; j < 4; ++j)
                acc[i * 4 + j] = __builtin_amdgcn_mfma_scale_f32_16x16x128_f8f6f4(
                    a8[i], b8[j], acc[i * 4 + j], 0, 0, 0, SCALE_BYTE, 0, SCALE_BYTE);
        __syncthreads();   // all waves done reading before next stage
    }

    // epilogue. C layout: col = lane&15, row = (lane>>4)*4 + reg (16x16 shape)
    const int dp = dper[0];
#pragma unroll
    for (int i = 0; i < 4; ++i)
#pragma unroll
        for (int r = 0; r < 4; ++r) {
            const int gr   = qbase + (wave >> 1) * 64 + 16 * i + 4 * lquad + r;
            const int pcol = gr * dp - dbase;   // local col of positive, if here
            float e = 0.0f;
#pragma unroll
            for (int j = 0; j < 4; ++j) {
                float v = acc[i * 4 + j][r];
                if ((wave & 1) * 64 + 16 * j + lm == pcol) pos[gr] = v * TEMP_INV;
                e += __expf(v * TEMP_INV);
            }
            e += __shfl_xor(e, 1);
            e += __shfl_xor(e, 2);
            e += __shfl_xor(e, 4);
            e += __shfl_xor(e, 8);
            if (lm == 0) atomicAdd(&rowsum[gr], e);
        }
}

// ---------------- final: loss = sum(log(rowsum) - pos)/B ----------------
__global__ void final_kernel(const float* __restrict__ rowsum,
                             const float* __restrict__ pos,
                             float* __restrict__ out, int B) {
    __shared__ float red[16];
    int tid = threadIdx.x;   // 1024 threads
    float s = 0.0f;
    for (int i = tid; i < B; i += blockDim.x)
        s += __logf(rowsum[i]) - pos[i];
    s += __shfl_xor(s, 32);
    s += __shfl_xor(s, 16);
    s += __shfl_xor(s, 8);
    s += __shfl_xor(s, 4);
    s += __shfl_xor(s, 2);
    s += __shfl_xor(s, 1);
    int w = tid >> 6, l = tid & 63;
    if (l == 0) red[w] = s;
    __syncthreads();
    if (tid == 0) {
        float t = 0.0f;
        int nw = blockDim.x >> 6;
        for (int i = 0; i < nw; ++i) t += red[i];
        out[0] = t / (float)B;
    }
}

extern "C" void kernel_launch(void* const* d_in, const int* in_sizes, int n_in,
                              void* d_out, int out_size, void* d_ws, size_t ws_size,
                              hipStream_t stream) {
    const float* Q   = (const float*)d_in[0];
    const float* Dm  = (const float*)d_in[1];
    const int* dper  = (const int*)d_in[2];
    float* out = (float*)d_out;

    const int DIM  = 1024;
    const int B    = in_sizes[0] / DIM;   // 4096
    const int Ntot = in_sizes[1] / DIM;   // 8192

    unsigned int* Q8 = (unsigned int*)d_ws;
    unsigned int* D8 = Q8 + (size_t)B * DIM / 4;
    float* rowsum = (float*)(D8 + (size_t)Ntot * DIM / 4);
    float* pos = rowsum + B;

    const int qSlots = B * DIM / 16;            // 262144
    const int dSlots = Ntot * DIM / 16;         // 524288
    cvt_kernel<<<(qSlots + dSlots) / 256, 256, 0, stream>>>(
        Q, Dm, Q8, D8, rowsum, qSlots, B, DIM);

    dim3 grid(B / 128, Ntot / 128);
    gemm_expsum_kernel<<<grid, 256, 0, stream>>>(Q8, D8, dper, rowsum, pos, DIM);

    final_kernel<<<1, 1024, 0, stream>>>(rowsum, pos, out, B);
}